// Round 15
// baseline (1703.763 us; speedup 1.0000x reference)
//
#include <hip/hip_runtime.h>
#include <hip/hip_bf16.h>

#define NBLK 64
#define NTHR 256

typedef __attribute__((ext_vector_type(8))) short short8;
typedef __attribute__((ext_vector_type(4))) float f32x4;

constexpr int B = 32, T = 512, D = 1024;
constexpr int JW = D / NBLK;           // 16 h-columns per block (= per tile)
constexpr int KW = D / 4;              // 256 K-elements per wave
static_assert(JW * NBLK == D, "partition");

// ws layout (136 KB):
//   0     : flags, 8 replicas x 256 u32 (1 KB each); flag id = 4*blk+wv (memset 0)
//   8192  : sq [2 slot][64 tile][256 u32] ring (128 KB, memset 0xFF)
// tile = 1 KB: [row32][colpair8] u32, written by block `tile` thread-linear.
// Published u32 LSB = epoch (step>>1)&1 (low-bf16 ulp). Data self-validates;
// flags are a fire-and-forget HINT that throttles the retry loop only.
// Ring-2 safety: C publishes s_{t+1} only after its slot-t loads retired; any
// P publishes s_{t+2} (same slot) only after passing step-t+1 check, which
// requires C's s_{t+1} -> overwrite strictly after read. Same-thread stores to
// the same address serialize, so slot content is only ever t or t-2 (opposite
// epoch LSB -> detectable).

__device__ __forceinline__ unsigned short f2bf(float f) {
  unsigned u = __builtin_bit_cast(unsigned, f);
  u += 0x7FFFu + ((u >> 16) & 1u);     // RNE
  return (unsigned short)(u >> 16);
}

__device__ __forceinline__ float sigm(float v) {
  return 1.0f / (1.0f + __expf(-v));
}

__device__ __forceinline__ float tanh_fast(float v) {
  v = fminf(fmaxf(v, -30.0f), 30.0f);
  float e = __expf(2.0f * v);
  return (e - 1.0f) / (e + 1.0f);
}

// proven coherence path: bypass L1+L2, coherent at LLC
__device__ __forceinline__ void st_u32_llc(unsigned* p, unsigned v) {
  asm volatile("global_store_dword %0, %1, off sc0 sc1" :: "v"(p), "v"(v) : "memory");
}

struct u32x4s { unsigned x, y, z, w; };

__global__ void __launch_bounds__(NTHR, 1) lstm_persistent(
    const float* __restrict__ x,
    const float* __restrict__ W1, const float* __restrict__ b1,
    const float* __restrict__ W2, const float* __restrict__ b2,
    const float* __restrict__ W3, const float* __restrict__ b3,
    const float* __restrict__ W4, const float* __restrict__ b4,
    const float* __restrict__ bias,
    float* __restrict__ out,            // [B,T,D] ++ cT [B,D] ++ hT [B,D]
    unsigned* __restrict__ flags,       // 8 replicas x 256 per-wave step flags
    unsigned* __restrict__ sq)          // [2][64][256] u32 tile-major s ring
{
  __shared__ float zx[2][4][B][72];     // parity-doubled; pad 72 -> 2-way only

  const int blk  = blockIdx.x;
  const int tid  = threadIdx.x;
  const int wv   = tid >> 6;
  const int lane = tid & 63;
  const int j0   = blk * JW;
  const int rot  = blk & 7;             // K-slice rotation + flag replica

  // consumer-role mapping (MFMA fragments)
  const int m     = lane & 15;          // A-row (tile0); +16 for tile1
  const int kg    = (lane >> 4) * 8;    // k sub-offset within a K=32 step
  const int kbase = wv * KW;

  // ---- one-time: weights for all 4 gates over this wave's K slice ----
  const float* Wg[4] = {W1, W2, W3, W4};
  short8 bfrag[4][8];
#pragma unroll
  for (int g = 0; g < 4; ++g) {
    const float* wrow = Wg[g] + (size_t)(j0 + m) * D + kbase;
#pragma unroll
    for (int kk = 0; kk < 8; ++kk) {
      const int kkr = (kk + rot) & 7;
      float4 fa = *(const float4*)(wrow + kkr * 32 + kg);
      float4 fb = *(const float4*)(wrow + kkr * 32 + kg + 4);
      short8 v;
      v[0] = (short)f2bf(fa.x); v[1] = (short)f2bf(fa.y);
      v[2] = (short)f2bf(fa.z); v[3] = (short)f2bf(fa.w);
      v[4] = (short)f2bf(fb.x); v[5] = (short)f2bf(fb.y);
      v[6] = (short)f2bf(fb.z); v[7] = (short)f2bf(fb.w);
      bfrag[g][kk] = v;
    }
  }

  // producer/gate-math mapping: tid -> (row gb, colpair jp)
  const int gb   = tid >> 3;            // 0..31
  const int jp   = (tid & 7) * 2;       // 0,2,..,14
  const int jcol = j0 + jp;

  const float bsum0 = bias[jcol], bsum1 = bias[jcol + 1];
  const float bf0 = b1[jcol] + bsum0, bf1 = b1[jcol + 1] + bsum1;
  const float bi0 = b2[jcol] + bsum0, bi1 = b2[jcol + 1] + bsum1;
  const float bg0 = b3[jcol] + bsum0, bg1 = b3[jcol + 1] + bsum1;
  const float bo0 = b4[jcol] + bsum0, bo1 = b4[jcol + 1] + bsum1;

  const float* xrow = x + (size_t)gb * T * D + jcol;
  float* outrow     = out + (size_t)gb * T * D + jcol;
  float* cTp        = out + (size_t)B * T * D + (size_t)gb * D + jcol;
  float* hTp        = cTp + (size_t)B * D;

  // ---- prologue: publish s_0 (epoch 0) + flag, fully fire-and-forget ----
  {
    float2 x0 = *(const float2*)xrow;
    unsigned v = ((unsigned)f2bf(x0.x) | ((unsigned)f2bf(x0.y) << 16)) & ~1u;
    st_u32_llc(sq + blk * 256 + tid, v);
    if (lane < 8) st_u32_llc(flags + lane * 256 + 4 * blk + wv, 1u);
  }

  // A-load base (u16 units): tile (kbase>>4)+(kg>>4), row m, col (kg&8)
  const int aoff = ((kbase >> 4) + (kg >> 4)) * 512 + m * 16 + (kg & 8);
  const unsigned* pollp = flags + rot * 256 + 64 * wv + lane;

  float c0 = 0.0f, c1 = 0.0f;
  unsigned rA = 0, rB = 0;   // flag-poll regs, live across whole body

  for (int t = 0; t < T; ++t) {
    // x[t+1] prefetch (retires under the A-load window's waits)
    const int tn = (t + 1 < T) ? (t + 1) : (T - 1);
    float2 xv;
    asm volatile("global_load_dwordx2 %0, %1, off"
                 : "=v"(xv) : "v"(xrow + (size_t)tn * D));

    const unsigned short* ap =
        (const unsigned short*)sq + (size_t)(t & 1) * 32768 + aoff;
    const unsigned eexp = (unsigned)(t >> 1) & 1u;
    short8 a0[8], a1[8];

    // ---- attempt-0: speculative loads + counted-wait epoch check (no MFMA) --
#pragma unroll
    for (int kk = 0; kk < 8; ++kk) {
      const int kkr = (kk + rot) & 7;
      asm volatile("global_load_dwordx4 %0, %1, off sc0 sc1"
                   : "=v"(a0[kk]) : "v"(ap + kkr * 1024));
      asm volatile("global_load_dwordx4 %0, %1, off sc0 sc1"
                   : "=v"(a1[kk]) : "v"(ap + kkr * 1024 + 256));
    }
    unsigned orv = 0u, andv = 0xFFFFFFFFu;
    // queue: [s][flag][out][x][A0 A0' .. A7 A7'] (prologue/t=0 variants give
    // the same exact counts). Before kk's check: vmcnt(14-2kk); kk7 drains all.
#define CHK_KK(kk, NSTR)                                                      \
    asm volatile("s_waitcnt vmcnt(" NSTR ")" ::: "memory");                   \
    __builtin_amdgcn_sched_barrier(0);                                        \
    {                                                                         \
      u32x4s q0 = __builtin_bit_cast(u32x4s, a0[kk]);                         \
      u32x4s q1 = __builtin_bit_cast(u32x4s, a1[kk]);                         \
      orv  |= q0.x | q0.y | q0.z | q0.w | q1.x | q1.y | q1.z | q1.w;          \
      andv &= q0.x & q0.y & q0.z & q0.w & q1.x & q1.y & q1.z & q1.w;          \
    }
    CHK_KK(0, "14") CHK_KK(1, "12") CHK_KK(2, "10") CHK_KK(3, "8")
    CHK_KK(4, "6")  CHK_KK(5, "4")  CHK_KK(6, "2")  CHK_KK(7, "0")
#undef CHK_KK
    {
      unsigned bad = eexp ? (~andv & 1u) : (orv & 1u);
      if (!__all((int)(bad == 0u))) {
        // ---- cheap retry: 2-deep flag poll (256B/wave/round) ----
        const unsigned tgt = (unsigned)(t + 1);
        int guard = 0;
        asm volatile("global_load_dword %0, %1, off sc0 sc1" : "=v"(rA) : "v"(pollp));
        for (;;) {
          asm volatile("global_load_dword %0, %1, off sc0 sc1" : "=v"(rB) : "v"(pollp));
          asm volatile("s_waitcnt vmcnt(1)" ::: "memory");
          __builtin_amdgcn_sched_barrier(0);
          if (__all((int)(rA >= tgt))) break;
          asm volatile("global_load_dword %0, %1, off sc0 sc1" : "=v"(rA) : "v"(pollp));
          asm volatile("s_waitcnt vmcnt(1)" ::: "memory");
          __builtin_amdgcn_sched_barrier(0);
          if (__all((int)(rB >= tgt))) break;
          if (++guard > (1 << 21)) break;   // fail loud, never hang
        }
        // ---- reload + verify (flag lags data issue -> almost always 1 round) --
        int g2 = 0;
        for (;;) {
#pragma unroll
          for (int kk = 0; kk < 8; ++kk) {
            const int kkr = (kk + rot) & 7;
            asm volatile("global_load_dwordx4 %0, %1, off sc0 sc1"
                         : "=v"(a0[kk]) : "v"(ap + kkr * 1024));
            asm volatile("global_load_dwordx4 %0, %1, off sc0 sc1"
                         : "=v"(a1[kk]) : "v"(ap + kkr * 1024 + 256));
          }
          asm volatile("s_waitcnt vmcnt(0)" ::: "memory");
          __builtin_amdgcn_sched_barrier(0);
          unsigned o2 = 0u, a2 = 0xFFFFFFFFu;
#pragma unroll
          for (int kk = 0; kk < 8; ++kk) {
            u32x4s q0 = __builtin_bit_cast(u32x4s, a0[kk]);
            u32x4s q1 = __builtin_bit_cast(u32x4s, a1[kk]);
            o2 |= q0.x | q0.y | q0.z | q0.w | q1.x | q1.y | q1.z | q1.w;
            a2 &= q0.x & q0.y & q0.z & q0.w & q1.x & q1.y & q1.z & q1.w;
          }
          unsigned b2 = eexp ? (~a2 & 1u) : (o2 & 1u);
          if (__all((int)(b2 == 0u))) break;
          if (++g2 > (1 << 12)) break;      // fail loud, never hang
        }
      }
    }
    __builtin_amdgcn_sched_barrier(0);      // fence: no MFMA above the waits

    // ---- single MFMA pass on verified data ----
    f32x4 acc[2][4];
#pragma unroll
    for (int mt = 0; mt < 2; ++mt)
#pragma unroll
      for (int g = 0; g < 4; ++g) acc[mt][g] = (f32x4){0.f, 0.f, 0.f, 0.f};
#pragma unroll
    for (int kk = 0; kk < 8; ++kk)
#pragma unroll
      for (int g = 0; g < 4; ++g) {
        acc[0][g] = __builtin_amdgcn_mfma_f32_16x16x32_bf16(a0[kk], bfrag[g][kk], acc[0][g], 0, 0, 0);
        acc[1][g] = __builtin_amdgcn_mfma_f32_16x16x32_bf16(a1[kk], bfrag[g][kk], acc[1][g], 0, 0, 0);
      }

    // ---- exchange partials into parity buffer; ONE barrier per step ----
    const int pz = t & 1;
    {
      const int zr = (lane >> 4) * 4;
#pragma unroll
      for (int g = 0; g < 4; ++g)
#pragma unroll
        for (int r = 0; r < 4; ++r) {
          zx[pz][wv][zr + r][g * 16 + m]      = acc[0][g][r];
          zx[pz][wv][zr + r + 16][g * 16 + m] = acc[1][g][r];
        }
    }
    __syncthreads();

    // ---- reduce 4 K-partials + gate math for (gb, jcol/jcol+1) ----
    float zf0, zf1, zi0, zi1, zg0, zg1, zo0, zo1;
    {
      float2 f_ = *(const float2*)&zx[pz][0][gb][jp];
      float2 i_ = *(const float2*)&zx[pz][0][gb][16 + jp];
      float2 g_ = *(const float2*)&zx[pz][0][gb][32 + jp];
      float2 o_ = *(const float2*)&zx[pz][0][gb][48 + jp];
      zf0 = f_.x; zf1 = f_.y; zi0 = i_.x; zi1 = i_.y;
      zg0 = g_.x; zg1 = g_.y; zo0 = o_.x; zo1 = o_.y;
#pragma unroll
      for (int w = 1; w < 4; ++w) {
        f_ = *(const float2*)&zx[pz][w][gb][jp];
        i_ = *(const float2*)&zx[pz][w][gb][16 + jp];
        g_ = *(const float2*)&zx[pz][w][gb][32 + jp];
        o_ = *(const float2*)&zx[pz][w][gb][48 + jp];
        zf0 += f_.x; zf1 += f_.y; zi0 += i_.x; zi1 += i_.y;
        zg0 += g_.x; zg1 += g_.y; zo0 += o_.x; zo1 += o_.y;
      }
    }

    float f0 = sigm(zf0 + bf0), f1 = sigm(zf1 + bf1);
    float i0 = sigm(zi0 + bi0) * tanh_fast(zg0 + bg0);
    float i1 = sigm(zi1 + bi1) * tanh_fast(zg1 + bg1);
    c0 = c0 * f0 + i0;
    c1 = c1 * f1 + i1;
    float h0 = sigm(zo0 + bo0) * tanh_fast(c0);
    float h1 = sigm(zo1 + bo1) * tanh_fast(c1);

    if (t + 1 < T) {
      // fully drain-free publish: s-store (epoch LSB), flag hint, out-store
      const unsigned epub = (unsigned)((t + 1) >> 1) & 1u;
      unsigned v = (((unsigned)f2bf(h0 + xv.x) |
                     ((unsigned)f2bf(h1 + xv.y) << 16)) & ~1u) | epub;
      st_u32_llc(sq + (size_t)((t + 1) & 1) * 16384 + blk * 256 + tid, v);
      if (lane < 8) st_u32_llc(flags + lane * 256 + 4 * blk + wv, (unsigned)(t + 2));
      *(float2*)(outrow + (size_t)t * D) = make_float2(h0, h1);
    } else {
      *(float2*)(outrow + (size_t)t * D) = make_float2(h0, h1);
      *(float2*)cTp = make_float2(c0, c1);
      *(float2*)hTp = make_float2(h0, h1);
    }

    // keep-alive: pin poll regs + xv so an outstanding flag load can never
    // land in a reallocated register
    asm volatile("" :: "v"(rA), "v"(rB), "v"(xv));
  }
}

extern "C" void kernel_launch(void* const* d_in, const int* in_sizes, int n_in,
                              void* d_out, int out_size, void* d_ws, size_t ws_size,
                              hipStream_t stream) {
  const float* x    = (const float*)d_in[0];
  const float* W1   = (const float*)d_in[1];
  const float* b1   = (const float*)d_in[2];
  const float* W2   = (const float*)d_in[3];
  const float* b2   = (const float*)d_in[4];
  const float* W3   = (const float*)d_in[5];
  const float* b3   = (const float*)d_in[6];
  const float* W4   = (const float*)d_in[7];
  const float* b4   = (const float*)d_in[8];
  const float* bias = (const float*)d_in[9];

  unsigned* flags = (unsigned*)d_ws;                    // 8 replicas x 1 KB
  unsigned* sq    = (unsigned*)((char*)d_ws + 8192);    // [2][64][256] u32 ring

  hipMemsetAsync(d_ws, 0, 8192, stream);                    // flags = 0
  hipMemsetAsync((char*)d_ws + 8192, 0xFF, 131072, stream); // sq LSB=1 (stale)
  hipLaunchKernelGGL(lstm_persistent, dim3(NBLK), dim3(NTHR), 0, stream,
                     x, W1, b1, W2, b2, W3, b3, W4, b4, bias,
                     (float*)d_out, flags, sq);
}

// Round 16
// 1602.340 us; speedup vs baseline: 1.0633x; 1.0633x over previous
//
#include <hip/hip_runtime.h>
#include <hip/hip_bf16.h>

#define NBLK 64
#define NTHR 256

typedef __attribute__((ext_vector_type(8))) short short8;
typedef __attribute__((ext_vector_type(4))) float f32x4;

constexpr int B = 32, T = 512, D = 1024;
constexpr int JW = D / NBLK;           // 16 h-columns per block (= per tile)
constexpr int KW = D / 4;              // 256 K-elements per wave
static_assert(JW * NBLK == D, "partition");

// ws layout (128 KB): sq [2 slot][64 tile][256 u32], memset 0xFF.
// tile = 1 KB: [row32][colpair8] u32, written by block `tile` thread-linear.
// Published u32 LSB = epoch (step>>1)&1 (low-bf16 ulp). Data self-validates;
// NO flags, NO drains. Ring-2 safety: any P publishes s_{t+2} (same slot as
// s_t) only after passing step-t+1's check, which requires consumer C's
// s_{t+1}, which C publishes only after consuming slot-t. Same-thread stores
// to one address serialize, so a slot word is only ever t or t-2 content —
// opposite epoch LSB, detectable per-word (torn mixes included).

__device__ __forceinline__ unsigned short f2bf(float f) {
  unsigned u = __builtin_bit_cast(unsigned, f);
  u += 0x7FFFu + ((u >> 16) & 1u);     // RNE
  return (unsigned short)(u >> 16);
}

__device__ __forceinline__ float sigm(float v) {
  return 1.0f / (1.0f + __expf(-v));
}

__device__ __forceinline__ float tanh_fast(float v) {
  v = fminf(fmaxf(v, -30.0f), 30.0f);
  float e = __expf(2.0f * v);
  return (e - 1.0f) / (e + 1.0f);
}

// proven coherence path: bypass L1+L2, coherent at LLC
__device__ __forceinline__ void st_u32_llc(unsigned* p, unsigned v) {
  asm volatile("global_store_dword %0, %1, off sc0 sc1" :: "v"(p), "v"(v) : "memory");
}

struct u32x4s { unsigned x, y, z, w; };

// wave-uniform epoch check over one 32-u32x2 fragment set (single tree)
__device__ __forceinline__ int check_set(const short8* a0, const short8* a1,
                                         unsigned eexp) {
  unsigned r;
  if (eexp) {                 // expect LSB==1 everywhere: AND-tree
    r = 0xFFFFFFFFu;
#pragma unroll
    for (int kk = 0; kk < 8; ++kk) {
      u32x4s q0 = __builtin_bit_cast(u32x4s, a0[kk]);
      u32x4s q1 = __builtin_bit_cast(u32x4s, a1[kk]);
      r &= q0.x & q0.y & q0.z & q0.w & q1.x & q1.y & q1.z & q1.w;
    }
    return __all((int)(r & 1u));
  } else {                    // expect LSB==0 everywhere: OR-tree
    r = 0u;
#pragma unroll
    for (int kk = 0; kk < 8; ++kk) {
      u32x4s q0 = __builtin_bit_cast(u32x4s, a0[kk]);
      u32x4s q1 = __builtin_bit_cast(u32x4s, a1[kk]);
      r |= q0.x | q0.y | q0.z | q0.w | q1.x | q1.y | q1.z | q1.w;
    }
    return __all((int)((r & 1u) == 0u));
  }
}

__global__ void __launch_bounds__(NTHR, 1) lstm_persistent(
    const float* __restrict__ x,
    const float* __restrict__ W1, const float* __restrict__ b1,
    const float* __restrict__ W2, const float* __restrict__ b2,
    const float* __restrict__ W3, const float* __restrict__ b3,
    const float* __restrict__ W4, const float* __restrict__ b4,
    const float* __restrict__ bias,
    float* __restrict__ out,            // [B,T,D] ++ cT [B,D] ++ hT [B,D]
    unsigned* __restrict__ sq)          // [2][64][256] u32 tile-major s ring
{
  __shared__ float zx[2][4][B][72];     // parity-doubled; pad 72 -> 2-way only

  const int blk  = blockIdx.x;
  const int tid  = threadIdx.x;
  const int wv   = tid >> 6;
  const int lane = tid & 63;
  const int j0   = blk * JW;
  const int rot  = blk & 7;             // K-slice rotation (de-burst LLC lines)

  // consumer-role mapping (MFMA fragments)
  const int m     = lane & 15;          // A-row (tile0); +16 for tile1
  const int kg    = (lane >> 4) * 8;    // k sub-offset within a K=32 step
  const int kbase = wv * KW;

  // ---- one-time: weights for all 4 gates over this wave's K slice ----
  const float* Wg[4] = {W1, W2, W3, W4};
  short8 bfrag[4][8];
#pragma unroll
  for (int g = 0; g < 4; ++g) {
    const float* wrow = Wg[g] + (size_t)(j0 + m) * D + kbase;
#pragma unroll
    for (int kk = 0; kk < 8; ++kk) {
      const int kkr = (kk + rot) & 7;
      float4 fa = *(const float4*)(wrow + kkr * 32 + kg);
      float4 fb = *(const float4*)(wrow + kkr * 32 + kg + 4);
      short8 v;
      v[0] = (short)f2bf(fa.x); v[1] = (short)f2bf(fa.y);
      v[2] = (short)f2bf(fa.z); v[3] = (short)f2bf(fa.w);
      v[4] = (short)f2bf(fb.x); v[5] = (short)f2bf(fb.y);
      v[6] = (short)f2bf(fb.z); v[7] = (short)f2bf(fb.w);
      bfrag[g][kk] = v;
    }
  }

  // producer/gate-math mapping: tid -> (row gb, colpair jp)
  const int gb   = tid >> 3;            // 0..31
  const int jp   = (tid & 7) * 2;       // 0,2,..,14
  const int jcol = j0 + jp;

  const float bsum0 = bias[jcol], bsum1 = bias[jcol + 1];
  const float bf0 = b1[jcol] + bsum0, bf1 = b1[jcol + 1] + bsum1;
  const float bi0 = b2[jcol] + bsum0, bi1 = b2[jcol + 1] + bsum1;
  const float bg0 = b3[jcol] + bsum0, bg1 = b3[jcol + 1] + bsum1;
  const float bo0 = b4[jcol] + bsum0, bo1 = b4[jcol + 1] + bsum1;

  const float* xrow = x + (size_t)gb * T * D + jcol;
  float* outrow     = out + (size_t)gb * T * D + jcol;
  float* cTp        = out + (size_t)B * T * D + (size_t)gb * D + jcol;
  float* hTp        = cTp + (size_t)B * D;

  // ---- prologue: publish s_0 (epoch 0 = LSB clear), fire-and-forget ----
  {
    float2 x0 = *(const float2*)xrow;
    unsigned v = ((unsigned)f2bf(x0.x) | ((unsigned)f2bf(x0.y) << 16)) & ~1u;
    st_u32_llc(sq + blk * 256 + tid, v);
  }

  // A-load base (u16 units): tile (kbase>>4)+(kg>>4), row m, col (kg&8)
  const int aoff = ((kbase >> 4) + (kg >> 4)) * 512 + m * 16 + (kg & 8);

  float c0 = 0.0f, c1 = 0.0f;
  short8 a0A[8], a1A[8], a0B[8], a1B[8];   // two poll sets, live all step

#define ISSUE_SET(A0, A1)                                                     \
  do {                                                                        \
    _Pragma("unroll")                                                         \
    for (int kk = 0; kk < 8; ++kk) {                                          \
      const int kkr = (kk + rot) & 7;                                         \
      asm volatile("global_load_dwordx4 %0, %1, off sc0 sc1"                  \
                   : "=v"((A0)[kk]) : "v"(ap + kkr * 1024));                  \
      asm volatile("global_load_dwordx4 %0, %1, off sc0 sc1"                  \
                   : "=v"((A1)[kk]) : "v"(ap + kkr * 1024 + 256));            \
    }                                                                         \
  } while (0)

#define MFMA_ALL(A0, A1)                                                      \
  do {                                                                        \
    _Pragma("unroll")                                                         \
    for (int kk = 0; kk < 8; ++kk)                                            \
      _Pragma("unroll")                                                       \
      for (int g = 0; g < 4; ++g) {                                           \
        acc[0][g] = __builtin_amdgcn_mfma_f32_16x16x32_bf16((A0)[kk], bfrag[g][kk], acc[0][g], 0, 0, 0); \
        acc[1][g] = __builtin_amdgcn_mfma_f32_16x16x32_bf16((A1)[kk], bfrag[g][kk], acc[1][g], 0, 0, 0); \
      }                                                                       \
  } while (0)

  for (int t = 0; t < T; ++t) {
    // x[t+1] prefetch (oldest; retires under the first counted wait)
    const int tn = (t + 1 < T) ? (t + 1) : (T - 1);
    float2 xv;
    asm volatile("global_load_dwordx2 %0, %1, off"
                 : "=v"(xv) : "v"(xrow + (size_t)tn * D));

    const unsigned short* ap =
        (const unsigned short*)sq + (size_t)(t & 1) * 32768 + aoff;
    const unsigned eexp = (unsigned)(t >> 1) & 1u;

    // ---- 2-deep pipelined data poll; exits with good set in regs ----
    ISSUE_SET(a0A, a1A);
    ISSUE_SET(a0B, a1B);
    int sel = 0, guard = 0;
    for (;;) {
      // in-order retirement: vmcnt(16) == "set just checked is fully landed"
      asm volatile("s_waitcnt vmcnt(16)" ::: "memory");
      __builtin_amdgcn_sched_barrier(0);
      if (check_set(a0A, a1A, eexp)) { sel = 0; break; }   // leftover = B
      ISSUE_SET(a0A, a1A);
      asm volatile("s_waitcnt vmcnt(16)" ::: "memory");
      __builtin_amdgcn_sched_barrier(0);
      if (check_set(a0B, a1B, eexp)) { sel = 1; break; }   // leftover = A
      ISSUE_SET(a0B, a1B);
      if (++guard > (1 << 18)) { sel = 0; break; }         // fail loud
    }
    __builtin_amdgcn_sched_barrier(0);

    // ---- single MFMA pass on the verified set (wave-uniform branch) ----
    f32x4 acc[2][4];
#pragma unroll
    for (int mt = 0; mt < 2; ++mt)
#pragma unroll
      for (int g = 0; g < 4; ++g) acc[mt][g] = (f32x4){0.f, 0.f, 0.f, 0.f};
    if (sel == 0) MFMA_ALL(a0A, a1A);
    else          MFMA_ALL(a0B, a1B);

    // ---- exchange partials into parity buffer; ONE barrier per step ----
    const int pz = t & 1;
    {
      const int zr = (lane >> 4) * 4;
#pragma unroll
      for (int g = 0; g < 4; ++g)
#pragma unroll
        for (int r = 0; r < 4; ++r) {
          zx[pz][wv][zr + r][g * 16 + m]      = acc[0][g][r];
          zx[pz][wv][zr + r + 16][g * 16 + m] = acc[1][g][r];
        }
    }
    __syncthreads();

    // ---- reduce 4 K-partials + gate math for (gb, jcol/jcol+1) ----
    float zf0, zf1, zi0, zi1, zg0, zg1, zo0, zo1;
    {
      float2 f_ = *(const float2*)&zx[pz][0][gb][jp];
      float2 i_ = *(const float2*)&zx[pz][0][gb][16 + jp];
      float2 g_ = *(const float2*)&zx[pz][0][gb][32 + jp];
      float2 o_ = *(const float2*)&zx[pz][0][gb][48 + jp];
      zf0 = f_.x; zf1 = f_.y; zi0 = i_.x; zi1 = i_.y;
      zg0 = g_.x; zg1 = g_.y; zo0 = o_.x; zo1 = o_.y;
#pragma unroll
      for (int w = 1; w < 4; ++w) {
        f_ = *(const float2*)&zx[pz][w][gb][jp];
        i_ = *(const float2*)&zx[pz][w][gb][16 + jp];
        g_ = *(const float2*)&zx[pz][w][gb][32 + jp];
        o_ = *(const float2*)&zx[pz][w][gb][48 + jp];
        zf0 += f_.x; zf1 += f_.y; zi0 += i_.x; zi1 += i_.y;
        zg0 += g_.x; zg1 += g_.y; zo0 += o_.x; zo1 += o_.y;
      }
    }

    float f0 = sigm(zf0 + bf0), f1 = sigm(zf1 + bf1);
    float i0 = sigm(zi0 + bi0) * tanh_fast(zg0 + bg0);
    float i1 = sigm(zi1 + bi1) * tanh_fast(zg1 + bg1);
    c0 = c0 * f0 + i0;
    c1 = c1 * f1 + i1;
    float h0 = sigm(zo0 + bo0) * tanh_fast(c0);
    float h1 = sigm(zo0 * 0.0f + zo1 + bo1) * tanh_fast(c1);  // keep zo1 path

    if (t + 1 < T) {
      // fully drain-free publish: s-store with epoch LSB, then out-store
      const unsigned epub = (unsigned)((t + 1) >> 1) & 1u;
      unsigned v = (((unsigned)f2bf(h0 + xv.x) |
                     ((unsigned)f2bf(h1 + xv.y) << 16)) & ~1u) | epub;
      st_u32_llc(sq + (size_t)((t + 1) & 1) * 16384 + blk * 256 + tid, v);
      *(float2*)(outrow + (size_t)t * D) = make_float2(h0, h1);
    } else {
      *(float2*)(outrow + (size_t)t * D) = make_float2(h0, h1);
      *(float2*)cTp = make_float2(c0, c1);
      *(float2*)hTp = make_float2(h0, h1);
    }

    // keep-alive: pin BOTH poll sets (the leftover one has 16 loads still in
    // flight targeting these regs) + xv, to end of body. In-order retirement
    // makes next step's vmcnt(16) absorb them without extra drains.
#pragma unroll
    for (int kk = 0; kk < 8; ++kk)
      asm volatile("" :: "v"(a0A[kk]), "v"(a1A[kk]), "v"(a0B[kk]), "v"(a1B[kk]));
    asm volatile("" :: "v"(xv));
  }
#undef ISSUE_SET
#undef MFMA_ALL
}

extern "C" void kernel_launch(void* const* d_in, const int* in_sizes, int n_in,
                              void* d_out, int out_size, void* d_ws, size_t ws_size,
                              hipStream_t stream) {
  const float* x    = (const float*)d_in[0];
  const float* W1   = (const float*)d_in[1];
  const float* b1   = (const float*)d_in[2];
  const float* W2   = (const float*)d_in[3];
  const float* b2   = (const float*)d_in[4];
  const float* W3   = (const float*)d_in[5];
  const float* b3   = (const float*)d_in[6];
  const float* W4   = (const float*)d_in[7];
  const float* b4   = (const float*)d_in[8];
  const float* bias = (const float*)d_in[9];

  unsigned* sq = (unsigned*)d_ws;   // [2][64][256] u32 = 128 KB ring

  // 0xFF -> every word LSB=1: mismatches epoch-0 at t=0/1 until real data
  hipMemsetAsync(d_ws, 0xFF, 131072, stream);
  hipLaunchKernelGGL(lstm_persistent, dim3(NBLK), dim3(NTHR), 0, stream,
                     x, W1, b1, W2, b2, W3, b3, W4, b4, bias,
                     (float*)d_out, sq);
}

// Round 17
// 1543.126 us; speedup vs baseline: 1.1041x; 1.0384x over previous
//
#include <hip/hip_runtime.h>
#include <hip/hip_bf16.h>

#define NBLK 64
#define NTHR 256

typedef __attribute__((ext_vector_type(8))) short short8;
typedef __attribute__((ext_vector_type(4))) float f32x4;

constexpr int B = 32, T = 512, D = 1024;
constexpr int JW = D / NBLK;           // 16 h-columns per block (= per tile)
constexpr int KW = D / 4;              // 256 K-elements per wave
static_assert(JW * NBLK == D, "partition");

// ws layout (128 KB): sq [2 slot][64 tile][256 u32], memset 0xFF.
// tile = 1 KB: [row32][colpair8] u32, written by block `tile` thread-linear.
// Published u32 LSB = epoch (step>>1)&1 (low-bf16 ulp). Data self-validates;
// no flags, no drains (ring-2 proof in R15: slot content is only ever step-t
// or step-t-2 — opposite epoch — because overwrite is gated by the epoch
// check two steps of dataflow downstream; same-thread same-address stores
// serialize at the owning LLC slice).

__device__ __forceinline__ unsigned short f2bf(float f) {
  unsigned u = __builtin_bit_cast(unsigned, f);
  u += 0x7FFFu + ((u >> 16) & 1u);     // RNE
  return (unsigned short)(u >> 16);
}

__device__ __forceinline__ float sigm(float v) {
  return 1.0f / (1.0f + __expf(-v));
}

__device__ __forceinline__ float tanh_fast(float v) {
  v = fminf(fmaxf(v, -30.0f), 30.0f);
  float e = __expf(2.0f * v);
  return (e - 1.0f) / (e + 1.0f);
}

// proven coherence path: bypass L1+L2, coherent at LLC
__device__ __forceinline__ void st_u32_llc(unsigned* p, unsigned v) {
  asm volatile("global_store_dword %0, %1, off sc0 sc1" :: "v"(p), "v"(v) : "memory");
}

struct u32x4s { unsigned x, y, z, w; };

__global__ void __launch_bounds__(NTHR, 1) lstm_persistent(
    const float* __restrict__ x,
    const float* __restrict__ W1, const float* __restrict__ b1,
    const float* __restrict__ W2, const float* __restrict__ b2,
    const float* __restrict__ W3, const float* __restrict__ b3,
    const float* __restrict__ W4, const float* __restrict__ b4,
    const float* __restrict__ bias,
    float* __restrict__ out,            // [B,T,D] ++ cT [B,D] ++ hT [B,D]
    unsigned* __restrict__ sq)          // [2][64][256] u32 tile-major s ring
{
  __shared__ float zx[2][4][B][72];     // parity-doubled; pad 72 -> 2-way only

  const int blk  = blockIdx.x;
  const int tid  = threadIdx.x;
  const int wv   = tid >> 6;
  const int lane = tid & 63;
  const int j0   = blk * JW;
  const int rot  = blk & 7;             // K-slice rotation (spread producers)

  // consumer-role mapping (MFMA fragments)
  const int m     = lane & 15;          // A-row (tile0); +16 for tile1
  const int kg    = (lane >> 4) * 8;    // k sub-offset within a K=32 step
  const int kbase = wv * KW;

  // ---- one-time: weights for all 4 gates over this wave's K slice ----
  const float* Wg[4] = {W1, W2, W3, W4};
  short8 bfrag[4][8];
#pragma unroll
  for (int g = 0; g < 4; ++g) {
    const float* wrow = Wg[g] + (size_t)(j0 + m) * D + kbase;
#pragma unroll
    for (int kk = 0; kk < 8; ++kk) {
      const int kkr = (kk + rot) & 7;
      float4 fa = *(const float4*)(wrow + kkr * 32 + kg);
      float4 fb = *(const float4*)(wrow + kkr * 32 + kg + 4);
      short8 v;
      v[0] = (short)f2bf(fa.x); v[1] = (short)f2bf(fa.y);
      v[2] = (short)f2bf(fa.z); v[3] = (short)f2bf(fa.w);
      v[4] = (short)f2bf(fb.x); v[5] = (short)f2bf(fb.y);
      v[6] = (short)f2bf(fb.z); v[7] = (short)f2bf(fb.w);
      bfrag[g][kk] = v;
    }
  }

  // producer/gate-math mapping: tid -> (row gb, colpair jp)
  const int gb   = tid >> 3;            // 0..31
  const int jp   = (tid & 7) * 2;       // 0,2,..,14
  const int jcol = j0 + jp;

  const float bsum0 = bias[jcol], bsum1 = bias[jcol + 1];
  const float bf0 = b1[jcol] + bsum0, bf1 = b1[jcol + 1] + bsum1;
  const float bi0 = b2[jcol] + bsum0, bi1 = b2[jcol + 1] + bsum1;
  const float bg0 = b3[jcol] + bsum0, bg1 = b3[jcol + 1] + bsum1;
  const float bo0 = b4[jcol] + bsum0, bo1 = b4[jcol + 1] + bsum1;

  const float* xrow = x + (size_t)gb * T * D + jcol;
  float* outrow     = out + (size_t)gb * T * D + jcol;
  float* cTp        = out + (size_t)B * T * D + (size_t)gb * D + jcol;
  float* hTp        = cTp + (size_t)B * D;

  // ---- prologue: publish s_0 (epoch 0 = LSB clear), fire-and-forget ----
  {
    float2 x0 = *(const float2*)xrow;
    unsigned v = ((unsigned)f2bf(x0.x) | ((unsigned)f2bf(x0.y) << 16)) & ~1u;
    st_u32_llc(sq + blk * 256 + tid, v);
  }

  // A-load base (u16 units): tile (kbase>>4)+(kg>>4), row m, col (kg&8)
  const int aoff = ((kbase >> 4) + (kg >> 4)) * 512 + m * 16 + (kg & 8);

  float c0 = 0.0f, c1 = 0.0f;
  short8 a0[8], a1[8];

  for (int t = 0; t < T; ++t) {
    // x[t+1] prefetch (retires under the first counted wait)
    const int tn = (t + 1 < T) ? (t + 1) : (T - 1);
    float2 xv;
    asm volatile("global_load_dwordx2 %0, %1, off"
                 : "=v"(xv) : "v"(xrow + (size_t)tn * D));

    const unsigned short* ap =
        (const unsigned short*)sq + (size_t)(t & 1) * 32768 + aoff;
    const unsigned eexp = (unsigned)(t >> 1) & 1u;

    // ---- issue all 16 A-loads ----
#pragma unroll
    for (int kk = 0; kk < 8; ++kk) {
      const int kkr = (kk + rot) & 7;
      asm volatile("global_load_dwordx4 %0, %1, off sc0 sc1"
                   : "=v"(a0[kk]) : "v"(ap + kkr * 1024));
      asm volatile("global_load_dwordx4 %0, %1, off sc0 sc1"
                   : "=v"(a1[kk]) : "v"(ap + kkr * 1024 + 256));
    }

    f32x4 acc[2][4];
#pragma unroll
    for (int mt = 0; mt < 2; ++mt)
#pragma unroll
      for (int g = 0; g < 4; ++g) acc[mt][g] = (f32x4){0.f, 0.f, 0.f, 0.f};

    unsigned pend = 0u;   // wave-uniform pending-tile mask

    // per-pair: counted wait -> epoch check of THIS pair -> MFMA now or defer.
    // queue: [prev s-store][prev out-store][x][A0 A0' .. A7 A7'] -> pair kk
    // landed at vmcnt(14-2kk). (Prologue/t=0 give the same counts.)
#define PAIR_OK(kk, OKVAR)                                                    \
    {                                                                         \
      u32x4s q0 = __builtin_bit_cast(u32x4s, a0[kk]);                         \
      u32x4s q1 = __builtin_bit_cast(u32x4s, a1[kk]);                         \
      unsigned orv  = q0.x | q0.y | q0.z | q0.w | q1.x | q1.y | q1.z | q1.w;  \
      unsigned andv = q0.x & q0.y & q0.z & q0.w & q1.x & q1.y & q1.z & q1.w;  \
      unsigned bad = eexp ? (~andv & 1u) : (orv & 1u);                        \
      OKVAR = __all((int)(bad == 0u));                                        \
    }
#define MFMA_PAIR(kk)                                                         \
    _Pragma("unroll")                                                         \
    for (int g = 0; g < 4; ++g) {                                             \
      acc[0][g] = __builtin_amdgcn_mfma_f32_16x16x32_bf16(a0[kk], bfrag[g][kk], acc[0][g], 0, 0, 0); \
      acc[1][g] = __builtin_amdgcn_mfma_f32_16x16x32_bf16(a1[kk], bfrag[g][kk], acc[1][g], 0, 0, 0); \
    }
#define STEP_KK(kk, NSTR)                                                     \
    asm volatile("s_waitcnt vmcnt(" NSTR ")" ::: "memory");                   \
    __builtin_amdgcn_sched_barrier(0);                                        \
    {                                                                         \
      int ok_;                                                                \
      PAIR_OK(kk, ok_)                                                        \
      if (ok_) { MFMA_PAIR(kk) } else { pend |= (1u << kk); }                 \
    }
    STEP_KK(0, "14") STEP_KK(1, "12") STEP_KK(2, "10") STEP_KK(3, "8")
    STEP_KK(4, "6")  STEP_KK(5, "4")  STEP_KK(6, "2")  STEP_KK(7, "0")
#undef STEP_KK

    // ---- straggler loop: reissue ONLY pending pairs (32B/lane each) ----
    {
      int guard = 0;
      while (pend) {
#pragma unroll
        for (int kk = 0; kk < 8; ++kk)
          if (pend & (1u << kk)) {
            const int kkr = (kk + rot) & 7;
            asm volatile("global_load_dwordx4 %0, %1, off sc0 sc1"
                         : "=v"(a0[kk]) : "v"(ap + kkr * 1024));
            asm volatile("global_load_dwordx4 %0, %1, off sc0 sc1"
                         : "=v"(a1[kk]) : "v"(ap + kkr * 1024 + 256));
          }
        asm volatile("s_waitcnt vmcnt(0)" ::: "memory");
        __builtin_amdgcn_sched_barrier(0);
#pragma unroll
        for (int kk = 0; kk < 8; ++kk)
          if (pend & (1u << kk)) {
            int ok_;
            PAIR_OK(kk, ok_)
            if (ok_) { MFMA_PAIR(kk) pend &= ~(1u << kk); }
          }
        if (++guard > (1 << 16)) break;   // fail loud, never hang
      }
    }
#undef PAIR_OK
#undef MFMA_PAIR
    __builtin_amdgcn_sched_barrier(0);

    // ---- exchange partials into parity buffer; ONE barrier per step ----
    const int pz = t & 1;
    {
      const int zr = (lane >> 4) * 4;
#pragma unroll
      for (int g = 0; g < 4; ++g)
#pragma unroll
        for (int r = 0; r < 4; ++r) {
          zx[pz][wv][zr + r][g * 16 + m]      = acc[0][g][r];
          zx[pz][wv][zr + r + 16][g * 16 + m] = acc[1][g][r];
        }
    }
    __syncthreads();

    // ---- reduce 4 K-partials + gate math for (gb, jcol/jcol+1) ----
    float zf0, zf1, zi0, zi1, zg0, zg1, zo0, zo1;
    {
      float2 f_ = *(const float2*)&zx[pz][0][gb][jp];
      float2 i_ = *(const float2*)&zx[pz][0][gb][16 + jp];
      float2 g_ = *(const float2*)&zx[pz][0][gb][32 + jp];
      float2 o_ = *(const float2*)&zx[pz][0][gb][48 + jp];
      zf0 = f_.x; zf1 = f_.y; zi0 = i_.x; zi1 = i_.y;
      zg0 = g_.x; zg1 = g_.y; zo0 = o_.x; zo1 = o_.y;
#pragma unroll
      for (int w = 1; w < 4; ++w) {
        f_ = *(const float2*)&zx[pz][w][gb][jp];
        i_ = *(const float2*)&zx[pz][w][gb][16 + jp];
        g_ = *(const float2*)&zx[pz][w][gb][32 + jp];
        o_ = *(const float2*)&zx[pz][w][gb][48 + jp];
        zf0 += f_.x; zf1 += f_.y; zi0 += i_.x; zi1 += i_.y;
        zg0 += g_.x; zg1 += g_.y; zo0 += o_.x; zo1 += o_.y;
      }
    }

    float f0 = sigm(zf0 + bf0), f1 = sigm(zf1 + bf1);
    float i0 = sigm(zi0 + bi0) * tanh_fast(zg0 + bg0);
    float i1 = sigm(zi1 + bi1) * tanh_fast(zg1 + bg1);
    c0 = c0 * f0 + i0;
    c1 = c1 * f1 + i1;
    float h0 = sigm(zo0 + bo0) * tanh_fast(c0);
    float h1 = sigm(zo1 + bo1) * tanh_fast(c1);

    if (t + 1 < T) {
      // drain-free publish: s-store with epoch LSB, then out-store
      const unsigned epub = (unsigned)((t + 1) >> 1) & 1u;
      unsigned v = (((unsigned)f2bf(h0 + xv.x) |
                     ((unsigned)f2bf(h1 + xv.y) << 16)) & ~1u) | epub;
      st_u32_llc(sq + (size_t)((t + 1) & 1) * 16384 + blk * 256 + tid, v);
      *(float2*)(outrow + (size_t)t * D) = make_float2(h0, h1);
    } else {
      *(float2*)(outrow + (size_t)t * D) = make_float2(h0, h1);
      *(float2*)cTp = make_float2(c0, c1);
      *(float2*)hTp = make_float2(h0, h1);
    }

    asm volatile("" :: "v"(xv));
  }
}

extern "C" void kernel_launch(void* const* d_in, const int* in_sizes, int n_in,
                              void* d_out, int out_size, void* d_ws, size_t ws_size,
                              hipStream_t stream) {
  const float* x    = (const float*)d_in[0];
  const float* W1   = (const float*)d_in[1];
  const float* b1   = (const float*)d_in[2];
  const float* W2   = (const float*)d_in[3];
  const float* b2   = (const float*)d_in[4];
  const float* W3   = (const float*)d_in[5];
  const float* b3   = (const float*)d_in[6];
  const float* W4   = (const float*)d_in[7];
  const float* b4   = (const float*)d_in[8];
  const float* bias = (const float*)d_in[9];

  unsigned* sq = (unsigned*)d_ws;   // [2][64][256] u32 = 128 KB ring

  // 0xFF -> every word LSB=1: mismatches epoch-0 at t=0/1 until real data
  hipMemsetAsync(d_ws, 0xFF, 131072, stream);
  hipLaunchKernelGGL(lstm_persistent, dim3(NBLK), dim3(NTHR), 0, stream,
                     x, W1, b1, W2, b2, W3, b3, W4, b4, bias,
                     (float*)d_out, sq);
}

// Round 19
// 1540.997 us; speedup vs baseline: 1.1056x; 1.0014x over previous
//
#include <hip/hip_runtime.h>
#include <hip/hip_bf16.h>

#define NBLK 64
#define NTHR 256

typedef __attribute__((ext_vector_type(8))) short short8;
typedef __attribute__((ext_vector_type(4))) float f32x4;

constexpr int B = 32, T = 512, D = 1024;
constexpr int JW = D / NBLK;           // 16 h-columns per block (= per tile)
constexpr int KW = D / 4;              // 256 K-elements per wave
static_assert(JW * NBLK == D, "partition");

// ws layout (128 KB): sq [2 slot][64 tile][256 u32], memset 0xFF.
// tile = 1 KB: [row32][colpair8] u32, written by block `tile` thread-linear.
// Published u32 LSB = epoch (step>>1)&1 (low-bf16 ulp). Data self-validates;
// no flags, no drains (ring-2 proof: slot content is only ever step-t or
// step-t-2 — opposite epoch — because overwrite is gated by the epoch check
// two steps of dataflow downstream; same-thread same-address stores
// serialize at the owning LLC slice).

__device__ __forceinline__ unsigned short f2bf(float f) {
  unsigned u = __builtin_bit_cast(unsigned, f);
  u += 0x7FFFu + ((u >> 16) & 1u);     // RNE
  return (unsigned short)(u >> 16);
}

__device__ __forceinline__ float sigm(float v) {
  return 1.0f / (1.0f + __expf(-v));
}

__device__ __forceinline__ float tanh_fast(float v) {
  v = fminf(fmaxf(v, -30.0f), 30.0f);
  float e = __expf(2.0f * v);
  return (e - 1.0f) / (e + 1.0f);
}

// proven coherence path: bypass L1+L2, coherent at LLC
__device__ __forceinline__ void st_u32_llc(unsigned* p, unsigned v) {
  asm volatile("global_store_dword %0, %1, off sc0 sc1" :: "v"(p), "v"(v) : "memory");
}

struct u32x4s { unsigned x, y, z, w; };

__global__ void __launch_bounds__(NTHR, 1) lstm_persistent(
    const float* __restrict__ x,
    const float* __restrict__ W1, const float* __restrict__ b1,
    const float* __restrict__ W2, const float* __restrict__ b2,
    const float* __restrict__ W3, const float* __restrict__ b3,
    const float* __restrict__ W4, const float* __restrict__ b4,
    const float* __restrict__ bias,
    float* __restrict__ out,            // [B,T,D] ++ cT [B,D] ++ hT [B,D]
    unsigned* __restrict__ sq)          // [2][64][256] u32 tile-major s ring
{
  __shared__ float zx[2][4][B][72];     // parity-doubled; pad 72 -> 2-way only

  const int blk  = blockIdx.x;
  const int tid  = threadIdx.x;
  const int wv   = tid >> 6;
  const int lane = tid & 63;
  const int j0   = blk * JW;
  const int rot  = blk & 7;             // K-slice rotation (spread producers)

  // consumer-role mapping (MFMA fragments)
  const int m     = lane & 15;          // A-row (tile0); +16 for tile1
  const int kg    = (lane >> 4) * 8;    // k sub-offset within a K=32 step
  const int kbase = wv * KW;

  // ---- one-time: weights for all 4 gates over this wave's K slice ----
  const float* Wg[4] = {W1, W2, W3, W4};
  short8 bfrag[4][8];
#pragma unroll
  for (int g = 0; g < 4; ++g) {
    const float* wrow = Wg[g] + (size_t)(j0 + m) * D + kbase;
#pragma unroll
    for (int kk = 0; kk < 8; ++kk) {
      const int kkr = (kk + rot) & 7;
      float4 fa = *(const float4*)(wrow + kkr * 32 + kg);
      float4 fb = *(const float4*)(wrow + kkr * 32 + kg + 4);
      short8 v;
      v[0] = (short)f2bf(fa.x); v[1] = (short)f2bf(fa.y);
      v[2] = (short)f2bf(fa.z); v[3] = (short)f2bf(fa.w);
      v[4] = (short)f2bf(fb.x); v[5] = (short)f2bf(fb.y);
      v[6] = (short)f2bf(fb.z); v[7] = (short)f2bf(fb.w);
      bfrag[g][kk] = v;
    }
  }

  // producer/gate-math mapping: tid -> (row gb, colpair jp)
  const int gb   = tid >> 3;            // 0..31
  const int jp   = (tid & 7) * 2;       // 0,2,..,14
  const int jcol = j0 + jp;

  const float bsum0 = bias[jcol], bsum1 = bias[jcol + 1];
  const float bf0 = b1[jcol] + bsum0, bf1 = b1[jcol + 1] + bsum1;
  const float bi0 = b2[jcol] + bsum0, bi1 = b2[jcol + 1] + bsum1;
  const float bg0 = b3[jcol] + bsum0, bg1 = b3[jcol + 1] + bsum1;
  const float bo0 = b4[jcol] + bsum0, bo1 = b4[jcol + 1] + bsum1;

  const float* xrow = x + (size_t)gb * T * D + jcol;
  float* outrow     = out + (size_t)gb * T * D + jcol;
  float* cTp        = out + (size_t)B * T * D + (size_t)gb * D + jcol;
  float* hTp        = cTp + (size_t)B * D;

  // ---- prologue: publish s_0 (epoch 0 = LSB clear), fire-and-forget ----
  {
    float2 x0 = *(const float2*)xrow;
    unsigned v = ((unsigned)f2bf(x0.x) | ((unsigned)f2bf(x0.y) << 16)) & ~1u;
    st_u32_llc(sq + blk * 256 + tid, v);
  }

  // A-load base (u16 units): tile (kbase>>4)+(kg>>4), row m, col (kg&8)
  const int aoff = ((kbase >> 4) + (kg >> 4)) * 512 + m * 16 + (kg & 8);

  float c0 = 0.0f, c1 = 0.0f;
  short8 a0[8], a1[8];

  for (int t = 0; t < T; ++t) {
    // x[t+1] prefetch (retires under the first counted wait)
    const int tn = (t + 1 < T) ? (t + 1) : (T - 1);
    float2 xv;
    asm volatile("global_load_dwordx2 %0, %1, off"
                 : "=v"(xv) : "v"(xrow + (size_t)tn * D));

    const unsigned short* ap =
        (const unsigned short*)sq + (size_t)(t & 1) * 32768 + aoff;
    const unsigned eexp = (unsigned)(t >> 1) & 1u;

    // ---- issue all 16 A-loads ----
#pragma unroll
    for (int kk = 0; kk < 8; ++kk) {
      const int kkr = (kk + rot) & 7;
      asm volatile("global_load_dwordx4 %0, %1, off sc0 sc1"
                   : "=v"(a0[kk]) : "v"(ap + kkr * 1024));
      asm volatile("global_load_dwordx4 %0, %1, off sc0 sc1"
                   : "=v"(a1[kk]) : "v"(ap + kkr * 1024 + 256));
    }

    f32x4 acc[2][4];
#pragma unroll
    for (int mt = 0; mt < 2; ++mt)
#pragma unroll
      for (int g = 0; g < 4; ++g) acc[mt][g] = (f32x4){0.f, 0.f, 0.f, 0.f};

    unsigned pend = 0u;   // wave-uniform pending-tile mask

    // per-pair: counted wait -> epoch check of THIS pair -> MFMA now or defer.
    // queue: [prev s-store][prev out-store][x][A0 A0' .. A7 A7'] -> pair kk
    // landed at vmcnt(14-2kk). (Prologue/t=0 give the same counts.)
#define PAIR_OK(kk, OKVAR)                                                    \
    {                                                                         \
      u32x4s q0 = __builtin_bit_cast(u32x4s, a0[kk]);                         \
      u32x4s q1 = __builtin_bit_cast(u32x4s, a1[kk]);                         \
      unsigned orv  = q0.x | q0.y | q0.z | q0.w | q1.x | q1.y | q1.z | q1.w;  \
      unsigned andv = q0.x & q0.y & q0.z & q0.w & q1.x & q1.y & q1.z & q1.w;  \
      unsigned bad = eexp ? (~andv & 1u) : (orv & 1u);                        \
      OKVAR = __all((int)(bad == 0u));                                        \
    }
#define MFMA_PAIR(kk)                                                         \
    _Pragma("unroll")                                                         \
    for (int g = 0; g < 4; ++g) {                                             \
      acc[0][g] = __builtin_amdgcn_mfma_f32_16x16x32_bf16(a0[kk], bfrag[g][kk], acc[0][g], 0, 0, 0); \
      acc[1][g] = __builtin_amdgcn_mfma_f32_16x16x32_bf16(a1[kk], bfrag[g][kk], acc[1][g], 0, 0, 0); \
    }
#define STEP_KK(kk, NSTR)                                                     \
    asm volatile("s_waitcnt vmcnt(" NSTR ")" ::: "memory");                   \
    __builtin_amdgcn_sched_barrier(0);                                        \
    {                                                                         \
      int ok_;                                                                \
      PAIR_OK(kk, ok_)                                                        \
      if (ok_) { MFMA_PAIR(kk) } else { pend |= (1u << kk); }                 \
    }
    STEP_KK(0, "14") STEP_KK(1, "12") STEP_KK(2, "10") STEP_KK(3, "8")
    STEP_KK(4, "6")  STEP_KK(5, "4")  STEP_KK(6, "2")  STEP_KK(7, "0")
#undef STEP_KK

    // ---- straggler loop: reissue ONLY pending pairs (32B/lane each) ----
    {
      int guard = 0;
      while (pend) {
#pragma unroll
        for (int kk = 0; kk < 8; ++kk)
          if (pend & (1u << kk)) {
            const int kkr = (kk + rot) & 7;
            asm volatile("global_load_dwordx4 %0, %1, off sc0 sc1"
                         : "=v"(a0[kk]) : "v"(ap + kkr * 1024));
            asm volatile("global_load_dwordx4 %0, %1, off sc0 sc1"
                         : "=v"(a1[kk]) : "v"(ap + kkr * 1024 + 256));
          }
        asm volatile("s_waitcnt vmcnt(0)" ::: "memory");
        __builtin_amdgcn_sched_barrier(0);
#pragma unroll
        for (int kk = 0; kk < 8; ++kk)
          if (pend & (1u << kk)) {
            int ok_;
            PAIR_OK(kk, ok_)
            if (ok_) { MFMA_PAIR(kk) pend &= ~(1u << kk); }
          }
        if (++guard > (1 << 16)) break;   // fail loud, never hang
      }
    }
#undef PAIR_OK
#undef MFMA_PAIR
    __builtin_amdgcn_sched_barrier(0);

    // ---- exchange partials into parity buffer; ONE barrier per step ----
    const int pz = t & 1;
    {
      const int zr = (lane >> 4) * 4;
#pragma unroll
      for (int g = 0; g < 4; ++g)
#pragma unroll
        for (int r = 0; r < 4; ++r) {
          zx[pz][wv][zr + r][g * 16 + m]      = acc[0][g][r];
          zx[pz][wv][zr + r + 16][g * 16 + m] = acc[1][g][r];
        }
    }
    __syncthreads();

    // ---- reduce 4 K-partials + gate math for (gb, jcol/jcol+1) ----
    float zf0, zf1, zi0, zi1, zg0, zg1, zo0, zo1;
    {
      float2 f_ = *(const float2*)&zx[pz][0][gb][jp];
      float2 i_ = *(const float2*)&zx[pz][0][gb][16 + jp];
      float2 g_ = *(const float2*)&zx[pz][0][gb][32 + jp];
      float2 o_ = *(const float2*)&zx[pz][0][gb][48 + jp];
      zf0 = f_.x; zf1 = f_.y; zi0 = i_.x; zi1 = i_.y;
      zg0 = g_.x; zg1 = g_.y; zo0 = o_.x; zo1 = o_.y;
#pragma unroll
      for (int w = 1; w < 4; ++w) {
        f_ = *(const float2*)&zx[pz][w][gb][jp];
        i_ = *(const float2*)&zx[pz][w][gb][16 + jp];
        g_ = *(const float2*)&zx[pz][w][gb][32 + jp];
        o_ = *(const float2*)&zx[pz][w][gb][48 + jp];
        zf0 += f_.x; zf1 += f_.y; zi0 += i_.x; zi1 += i_.y;
        zg0 += g_.x; zg1 += g_.y; zo0 += o_.x; zo1 += o_.y;
      }
    }

    float f0 = sigm(zf0 + bf0), f1 = sigm(zf1 + bf1);
    float i0 = sigm(zi0 + bi0) * tanh_fast(zg0 + bg0);
    float i1 = sigm(zi1 + bi1) * tanh_fast(zg1 + bg1);
    c0 = c0 * f0 + i0;
    c1 = c1 * f1 + i1;
    float h0 = sigm(zo0 + bo0) * tanh_fast(c0);
    float h1 = sigm(zo1 + bo1) * tanh_fast(c1);

    if (t + 1 < T) {
      // drain-free publish: s-store with epoch LSB, then out-store
      const unsigned epub = (unsigned)((t + 1) >> 1) & 1u;
      unsigned v = (((unsigned)f2bf(h0 + xv.x) |
                     ((unsigned)f2bf(h1 + xv.y) << 16)) & ~1u) | epub;
      st_u32_llc(sq + (size_t)((t + 1) & 1) * 16384 + blk * 256 + tid, v);
      *(float2*)(outrow + (size_t)t * D) = make_float2(h0, h1);
    } else {
      *(float2*)(outrow + (size_t)t * D) = make_float2(h0, h1);
      *(float2*)cTp = make_float2(c0, c1);
      *(float2*)hTp = make_float2(h0, h1);
    }

    asm volatile("" :: "v"(xv));
  }
}

extern "C" void kernel_launch(void* const* d_in, const int* in_sizes, int n_in,
                              void* d_out, int out_size, void* d_ws, size_t ws_size,
                              hipStream_t stream) {
  const float* x    = (const float*)d_in[0];
  const float* W1   = (const float*)d_in[1];
  const float* b1   = (const float*)d_in[2];
  const float* W2   = (const float*)d_in[3];
  const float* b2   = (const float*)d_in[4];
  const float* W3   = (const float*)d_in[5];
  const float* b3   = (const float*)d_in[6];
  const float* W4   = (const float*)d_in[7];
  const float* b4   = (const float*)d_in[8];
  const float* bias = (const float*)d_in[9];

  unsigned* sq = (unsigned*)d_ws;   // [2][64][256] u32 = 128 KB ring

  // 0xFF -> every word LSB=1: mismatches epoch-0 at t=0/1 until real data
  hipMemsetAsync(d_ws, 0xFF, 131072, stream);
  hipLaunchKernelGGL(lstm_persistent, dim3(NBLK), dim3(NTHR), 0, stream,
                     x, W1, b1, W2, b2, W3, b3, W4, b4, bias,
                     (float*)d_out, sq);
}